// Round 5
// baseline (102.571 us; speedup 1.0000x reference)
//
#include <hip/hip_runtime.h>

#define NROWS  200000
#define M_ROWS 50000
#define NT     10
#define RPB    32     // rows per block in gather (4 waves x 8 rows)
#define GBLOCKS ((M_ROWS + RPB - 1) / RPB)   // 1563

typedef float v2f __attribute__((ext_vector_type(2)));

#if __has_builtin(__builtin_amdgcn_cvt_scalef32_pk_f32_fp4) && __has_builtin(__builtin_amdgcn_cvt_scalef32_pk_fp4_f32)
#define HW_FP4 1
#endif

// ---------------- fp4 e2m1 helpers (hw with sw fallback; self-consistent) ----------------
#ifdef HW_FP4
#define DECP(W, SEL) __builtin_amdgcn_cvt_scalef32_pk_f32_fp4((W), 1.0f, (SEL))
__device__ __forceinline__ unsigned enc4x(float a, float b, float c, float d) {
    unsigned w = 0;
    w = __builtin_amdgcn_cvt_scalef32_pk_fp4_f32(w, a, b, 1.0f, 0);
    w = __builtin_amdgcn_cvt_scalef32_pk_fp4_f32(w, c, d, 1.0f, 1);
    return w;  // low 16 bits = 4 fp4 values
}
#else
__device__ __forceinline__ float sw_dec_fp4(unsigned n) {
    n &= 0xFu;
    unsigned p = n & 7u, s = n >> 3;
    float v = (p < 2u) ? 0.5f * (float)p
                       : (1.0f + 0.5f * (float)(p & 1u)) * (float)(1u << ((p >> 1) - 1u));
    return s ? -v : v;
}
__device__ __forceinline__ v2f sw_decp(unsigned w, int sel) {
    unsigned byte = (w >> (8 * sel)) & 0xFFu;
    v2f r; r[0] = sw_dec_fp4(byte); r[1] = sw_dec_fp4(byte >> 4);
    return r;
}
#define DECP(W, SEL) sw_decp((W), (SEL))
__device__ __forceinline__ unsigned sw_enc_fp4(float y) {
    unsigned s = (__float_as_uint(y) >> 28) & 0x8u;
    float a = fabsf(y);
    unsigned p;
    if      (a >= 5.0f)  p = 7u;
    else if (a >= 3.5f)  p = 6u;
    else if (a >= 2.5f)  p = 5u;
    else if (a >= 1.75f) p = 4u;
    else if (a >= 1.25f) p = 3u;
    else if (a >= 0.75f) p = 2u;
    else if (a >= 0.25f) p = 1u;
    else                 p = 0u;
    return s | p;
}
__device__ __forceinline__ unsigned enc4x(float a, float b, float c, float d) {
    return sw_enc_fp4(a) | (sw_enc_fp4(b) << 4) | (sw_enc_fp4(c) << 8) | (sw_enc_fp4(d) << 12);
}
#endif

// ---------- pass 1: f32 -> fp4 table (per-row scaled) + inverse norms; also zero the counter ----------
__global__ __launch_bounds__(256) void conv_kernel(
    const float* __restrict__ feature,
    unsigned short* __restrict__ q16,    // NROWS x 64 ushorts (256 fp4 / row = 128 B)
    float* __restrict__ invn,
    int* __restrict__ counter) {
    if (blockIdx.x == 0 && threadIdx.x == 0) *counter = 0;

    const int wave = threadIdx.x >> 6, lane = threadIdx.x & 63;
    const long row = blockIdx.x * 4 + wave;          // grid = NROWS/4
    const float4 x = reinterpret_cast<const float4*>(feature)[row * 64 + lane];

    // per-row max for scaling (cancels exactly in cosine)
    float amax = fmaxf(fmaxf(fabsf(x.x), fabsf(x.y)), fmaxf(fabsf(x.z), fabsf(x.w)));
#pragma unroll
    for (int s = 1; s < 64; s <<= 1) amax = fmaxf(amax, __shfl_xor(amax, s, 64));
    const float r = 6.0f / fmaxf(amax, 1e-30f);

    const unsigned w = enc4x(x.x * r, x.y * r, x.z * r, x.w * r);
    q16[row * 64 + lane] = (unsigned short)w;

    // norm of the stored (dequantized) values -> quantization bias cancels in sim
    v2f d0 = DECP(w, 0), d1 = DECP(w, 1);
    float sq = d0[0]*d0[0] + d0[1]*d0[1] + d1[0]*d1[0] + d1[1]*d1[1];
#pragma unroll
    for (int s = 1; s < 64; s <<= 1) sq += __shfl_xor(sq, s, 64);
    if (lane == 0) invn[row] = 1.0f / fmaxf(sqrtf(sq), 1e-8f);
}

// ---------- pass 2: gather + cosine + loss + fused deterministic final reduce ----------
__global__ __launch_bounds__(256) void gather_kernel(
    const unsigned int* __restrict__ q,   // dword view of the fp4 table (32 dw / row)
    const float* __restrict__ invn,
    const int* __restrict__ tuples,
    float* __restrict__ partial,
    int* __restrict__ counter,
    float* __restrict__ out) {
    const int tid  = threadIdx.x;
    const int wave = tid >> 6;
    const int lane = tid & 63;
    const int grp  = lane >> 3;
    const int sub  = lane & 7;
    const int row  = blockIdx.x * RPB + wave * 8 + grp;

    float res = 0.0f;
    if (row < M_ROWS) {
        const uint4* qv = reinterpret_cast<const uint4*>(q);

        int idx[NT];
#pragma unroll
        for (int t = 0; t < NT; ++t) idx[t] = tuples[row * NT + t];

        // issue all gather loads first (deep MLP), then decode/FMA
        uint4 sv = qv[(long)row * 8 + sub];
        uint4 wv[NT];
#pragma unroll
        for (int t = 0; t < NT; ++t) wv[t] = qv[(long)idx[t] * 8 + sub];

        float inn[NT];
#pragma unroll
        for (int t = 0; t < NT; ++t) inn[t] = invn[idx[t]];
        const float ni = invn[row];

        float hs[32];
#define DEC8(W, O) { v2f p0 = DECP(W,0), p1 = DECP(W,1), p2 = DECP(W,2), p3 = DECP(W,3); \
        hs[O+0]=p0[0]; hs[O+1]=p0[1]; hs[O+2]=p1[0]; hs[O+3]=p1[1]; \
        hs[O+4]=p2[0]; hs[O+5]=p2[1]; hs[O+6]=p3[0]; hs[O+7]=p3[1]; }
        DEC8(sv.x, 0) DEC8(sv.y, 8) DEC8(sv.z, 16) DEC8(sv.w, 24)
#undef DEC8

        float dots[NT];
#pragma unroll
        for (int t = 0; t < NT; ++t) {
            float d = 0.0f;
#define ACC8(W, O) { v2f p0 = DECP(W,0), p1 = DECP(W,1), p2 = DECP(W,2), p3 = DECP(W,3); \
            d += hs[O+0]*p0[0] + hs[O+1]*p0[1] + hs[O+2]*p1[0] + hs[O+3]*p1[1] \
               + hs[O+4]*p2[0] + hs[O+5]*p2[1] + hs[O+6]*p3[0] + hs[O+7]*p3[1]; }
            ACC8(wv[t].x, 0) ACC8(wv[t].y, 8) ACC8(wv[t].z, 16) ACC8(wv[t].w, 24)
#undef ACC8
            dots[t] = d;
        }

        // 3-stage butterfly within each 8-lane group
#pragma unroll
        for (int s = 1; s < 8; s <<= 1) {
#pragma unroll
            for (int t = 0; t < NT; ++t) dots[t] += __shfl_xor(dots[t], s, 64);
        }

        float sim0 = 0.0f, den = 0.0f;
#pragma unroll
        for (int t = 0; t < NT; ++t) {
            float sim = dots[t] * ni * inn[t];
            if (t == 0) sim0 = sim;
            else        den += __expf(sim);   // TEMPERATURE == 1
        }
        res = __logf(den) - sim0;
    }

    __shared__ float ws[RPB];
    __shared__ int is_last;
    if (sub == 0) ws[wave * 8 + grp] = res;
    __syncthreads();
    if (tid == 0) {
        float s = 0.0f;
#pragma unroll
        for (int r = 0; r < RPB; ++r) s += ws[r];
        partial[blockIdx.x] = s;
        __threadfence();                       // make partial visible device-wide
        int old = atomicAdd(counter, 1);
        is_last = (old == GBLOCKS - 1) ? 1 : 0;
    }
    __syncthreads();

    if (is_last) {
        __threadfence();                       // acquire: see all partials
        __shared__ double sm[256];
        double acc = 0.0;
        for (int i = tid; i < GBLOCKS; i += 256) acc += (double)partial[i];
        sm[tid] = acc;
        __syncthreads();
        for (int s = 128; s > 0; s >>= 1) {
            if (tid < s) sm[tid] += sm[tid + s];
            __syncthreads();
        }
        if (tid == 0) out[0] = (float)(sm[0] / (double)M_ROWS);
    }
}

extern "C" void kernel_launch(void* const* d_in, const int* in_sizes, int n_in,
                              void* d_out, int out_size, void* d_ws, size_t ws_size,
                              hipStream_t stream) {
    const float* feature = (const float*)d_in[0];
    const int*   tuples  = (const int*)d_in[1];
    float* out = (float*)d_out;

    unsigned short* q16 = (unsigned short*)d_ws;                    // 25,600,000 B
    float* invn         = (float*)((char*)d_ws + 25600000);         //    800,000 B
    float* partial      = (float*)((char*)d_ws + 26400000);         //      6,252 B
    int*   counter      = (int*)((char*)d_ws + 26500000);

    conv_kernel<<<NROWS / 4, 256, 0, stream>>>(feature, q16, invn, counter);
    gather_kernel<<<GBLOCKS, 256, 0, stream>>>((const unsigned int*)q16, invn, tuples,
                                               partial, counter, out);
}

// Round 6
// 60.749 us; speedup vs baseline: 1.6884x; 1.6884x over previous
//
#include <hip/hip_runtime.h>

#define NROWS  200000
#define M_ROWS 50000
#define NT     10
#define RPB    32     // rows per block in gather (4 waves x 8 rows)

typedef float v2f __attribute__((ext_vector_type(2)));

#if __has_builtin(__builtin_amdgcn_cvt_scalef32_pk_f32_fp4) && __has_builtin(__builtin_amdgcn_cvt_scalef32_pk_fp4_f32)
#define HW_FP4 1
#endif

// ---------------- fp4 e2m1 helpers (hw with sw fallback; self-consistent) ----------------
#ifdef HW_FP4
#define DECP(W, SEL) __builtin_amdgcn_cvt_scalef32_pk_f32_fp4((W), 1.0f, (SEL))
__device__ __forceinline__ unsigned enc4x(float a, float b, float c, float d) {
    unsigned w = 0;
    w = __builtin_amdgcn_cvt_scalef32_pk_fp4_f32(w, a, b, 1.0f, 0);
    w = __builtin_amdgcn_cvt_scalef32_pk_fp4_f32(w, c, d, 1.0f, 1);
    return w;  // low 16 bits = 4 fp4 values
}
#else
__device__ __forceinline__ float sw_dec_fp4(unsigned n) {
    n &= 0xFu;
    unsigned p = n & 7u, s = n >> 3;
    float v = (p < 2u) ? 0.5f * (float)p
                       : (1.0f + 0.5f * (float)(p & 1u)) * (float)(1u << ((p >> 1) - 1u));
    return s ? -v : v;
}
__device__ __forceinline__ v2f sw_decp(unsigned w, int sel) {
    unsigned byte = (w >> (8 * sel)) & 0xFFu;
    v2f r; r[0] = sw_dec_fp4(byte); r[1] = sw_dec_fp4(byte >> 4);
    return r;
}
#define DECP(W, SEL) sw_decp((W), (SEL))
__device__ __forceinline__ unsigned sw_enc_fp4(float y) {
    unsigned s = (__float_as_uint(y) >> 28) & 0x8u;
    float a = fabsf(y);
    unsigned p;
    if      (a >= 5.0f)  p = 7u;
    else if (a >= 3.5f)  p = 6u;
    else if (a >= 2.5f)  p = 5u;
    else if (a >= 1.75f) p = 4u;
    else if (a >= 1.25f) p = 3u;
    else if (a >= 0.75f) p = 2u;
    else if (a >= 0.25f) p = 1u;
    else                 p = 0u;
    return s | p;
}
__device__ __forceinline__ unsigned enc4x(float a, float b, float c, float d) {
    return sw_enc_fp4(a) | (sw_enc_fp4(b) << 4) | (sw_enc_fp4(c) << 8) | (sw_enc_fp4(d) << 12);
}
#endif

// ---------- pass 1: pure quantize f32 -> fp4 table (per-row scaled) ----------
__global__ __launch_bounds__(256) void conv_kernel(
    const float* __restrict__ feature,
    unsigned short* __restrict__ q16) {   // NROWS x 64 ushorts (256 fp4 / row = 128 B)
    const int wave = threadIdx.x >> 6, lane = threadIdx.x & 63;
    const long row = blockIdx.x * 4 + wave;          // grid = NROWS/4
    const float4 x = reinterpret_cast<const float4*>(feature)[row * 64 + lane];

    // per-row max for scaling (cancels exactly in cosine)
    float amax = fmaxf(fmaxf(fabsf(x.x), fabsf(x.y)), fmaxf(fabsf(x.z), fabsf(x.w)));
#pragma unroll
    for (int s = 1; s < 64; s <<= 1) amax = fmaxf(amax, __shfl_xor(amax, s, 64));
    const float r = 6.0f / fmaxf(amax, 1e-30f);

    q16[row * 64 + lane] = (unsigned short)enc4x(x.x * r, x.y * r, x.z * r, x.w * r);
}

// ---------- pass 2: gather + cosine + loss; norms computed from the gathered bytes ----------
__global__ __launch_bounds__(256) void gather_kernel(
    const unsigned int* __restrict__ q,   // dword view of the fp4 table (32 dw / row)
    const int* __restrict__ tuples,
    float* __restrict__ partial) {
    const int tid  = threadIdx.x;
    const int wave = tid >> 6;
    const int lane = tid & 63;
    const int grp  = lane >> 3;
    const int sub  = lane & 7;
    const int row  = blockIdx.x * RPB + wave * 8 + grp;

    float res = 0.0f;
    if (row < M_ROWS) {
        const uint4* qv = reinterpret_cast<const uint4*>(q);

        int idx[NT];
#pragma unroll
        for (int t = 0; t < NT; ++t) idx[t] = tuples[row * NT + t];

        // self fragment: lane holds elements [sub*32, sub*32+32) as one uint4
        uint4 sv = qv[(long)row * 8 + sub];
        float hs[32];
#define DEC8(W, O) { v2f p0 = DECP(W,0), p1 = DECP(W,1), p2 = DECP(W,2), p3 = DECP(W,3); \
        hs[O+0]=p0[0]; hs[O+1]=p0[1]; hs[O+2]=p1[0]; hs[O+3]=p1[1]; \
        hs[O+4]=p2[0]; hs[O+5]=p2[1]; hs[O+6]=p3[0]; hs[O+7]=p3[1]; }
        DEC8(sv.x, 0) DEC8(sv.y, 8) DEC8(sv.z, 16) DEC8(sv.w, 24)
#undef DEC8
        float selfsq = 0.0f;
#pragma unroll
        for (int k = 0; k < 32; ++k) selfsq += hs[k] * hs[k];

        float dots[NT], sqs[NT];
#pragma unroll
        for (int t = 0; t < NT; ++t) {
            uint4 wv = qv[(long)idx[t] * 8 + sub];
            float d = 0.0f, s = 0.0f;
#define ACC8(W, O) { v2f p0 = DECP(W,0), p1 = DECP(W,1), p2 = DECP(W,2), p3 = DECP(W,3); \
            d += hs[O+0]*p0[0] + hs[O+1]*p0[1] + hs[O+2]*p1[0] + hs[O+3]*p1[1] \
               + hs[O+4]*p2[0] + hs[O+5]*p2[1] + hs[O+6]*p3[0] + hs[O+7]*p3[1]; \
            s += p0[0]*p0[0] + p0[1]*p0[1] + p1[0]*p1[0] + p1[1]*p1[1] \
               + p2[0]*p2[0] + p2[1]*p2[1] + p3[0]*p3[0] + p3[1]*p3[1]; }
            ACC8(wv.x, 0) ACC8(wv.y, 8) ACC8(wv.z, 16) ACC8(wv.w, 24)
#undef ACC8
            dots[t] = d; sqs[t] = s;
        }

        // 3-stage butterfly within each 8-lane group (21 values)
#pragma unroll
        for (int s = 1; s < 8; s <<= 1) {
            selfsq += __shfl_xor(selfsq, s, 64);
#pragma unroll
            for (int t = 0; t < NT; ++t) {
                dots[t] += __shfl_xor(dots[t], s, 64);
                sqs[t]  += __shfl_xor(sqs[t],  s, 64);
            }
        }

        const float ssq = fmaxf(selfsq, 1e-16f);
        float sim0 = 0.0f, den = 0.0f;
#pragma unroll
        for (int t = 0; t < NT; ++t) {
            float sim = dots[t] * rsqrtf(ssq * fmaxf(sqs[t], 1e-16f));
            if (t == 0) sim0 = sim;
            else        den += __expf(sim);   // TEMPERATURE == 1
        }
        res = __logf(den) - sim0;
    }

    __shared__ float ws[RPB];
    if (sub == 0) ws[wave * 8 + grp] = res;
    __syncthreads();
    if (tid == 0) {
        float s = 0.0f;
#pragma unroll
        for (int r = 0; r < RPB; ++r) s += ws[r];
        partial[blockIdx.x] = s;
    }
}

__global__ __launch_bounds__(256) void
final_reduce_kernel(const float* __restrict__ partial, int n,
                    float* __restrict__ out) {
    __shared__ double sm[256];
    double acc = 0.0;
    for (int i = threadIdx.x; i < n; i += 256) acc += (double)partial[i];
    sm[threadIdx.x] = acc;
    __syncthreads();
    for (int s = 128; s > 0; s >>= 1) {
        if (threadIdx.x < s) sm[threadIdx.x] += sm[threadIdx.x + s];
        __syncthreads();
    }
    if (threadIdx.x == 0) out[0] = (float)(sm[0] / (double)M_ROWS);
}

extern "C" void kernel_launch(void* const* d_in, const int* in_sizes, int n_in,
                              void* d_out, int out_size, void* d_ws, size_t ws_size,
                              hipStream_t stream) {
    const float* feature = (const float*)d_in[0];
    const int*   tuples  = (const int*)d_in[1];
    float* out = (float*)d_out;

    unsigned short* q16 = (unsigned short*)d_ws;                    // 25,600,000 B
    float* partial      = (float*)((char*)d_ws + 25600000);

    const int gblocks = (M_ROWS + RPB - 1) / RPB;                   // 1563

    conv_kernel<<<NROWS / 4, 256, 0, stream>>>(feature, q16);
    gather_kernel<<<gblocks, 256, 0, stream>>>((const unsigned int*)q16, tuples, partial);
    final_reduce_kernel<<<1, 256, 0, stream>>>(partial, gblocks, out);
}